// Round 1
// 1273.100 us; speedup vs baseline: 1.2066x; 1.2066x over previous
//
#include <hip/hip_runtime.h>
#include <hip/hip_bf16.h>
#include <math.h>

// AttDecoder: V=32000 E=512 H=512 B=16 T=128 S=512 D=2
// d_out: [2048x32000 out][2048x1536 attention_input][2048 targets], dtype f32 OR bf16
// (runtime-detected via k_detect). Internal compute: bf16 MFMA, fp32 accum.

typedef __attribute__((ext_vector_type(8))) short short8;
typedef __attribute__((ext_vector_type(4))) float floatx4;
typedef __attribute__((ext_vector_type(4))) int intx4;
typedef __hip_bfloat16 bf16;

__device__ __forceinline__ float b2f(bf16 v){ return __bfloat162float(v); }
__device__ __forceinline__ bf16 f2b(float v){ return __float2bfloat16(v); }
// dual-dtype load: f32 flag chooses float vs bf16 interpretation
__device__ __forceinline__ float ld(const void* p, long i, int f32){
  return f32 ? ((const float*)p)[i] : b2f(((const bf16*)p)[i]);
}

// ------------------------------------------------------------- detect
// true bf16 N(0,0.02): exponent fields ~[110,125] -> ~0 outliers.
// f32-as-bf16: even uint16s are mantissa halves, uniform exponents -> ~45% outliers.
__global__ void k_detect(const unsigned short* __restrict__ h0u, int* __restrict__ flags){
  if (threadIdx.x == 0){
    int bad = 0;
    for (int i=0;i<256;i++){
      int e = (h0u[i] >> 7) & 0xFF;
      if (e != 0 && (e < 100 || e > 140)) bad++;
    }
    flags[0] = (bad > 32) ? 1 : 0;   // 1 = inputs/outputs are float32
    flags[1] = 0;                     // lstm barrier counter
  }
}

// ---------------------------------------------------------------- prep
__global__ void k_prep(const int* __restrict__ x, const void* __restrict__ h0,
                       const void* __restrict__ c0, const void* __restrict__ emb,
                       const int* __restrict__ flags, bf16* __restrict__ lstm_input,
                       bf16* __restrict__ att_ws, float* __restrict__ state0,
                       bf16* __restrict__ hbuf){
  int f32 = flags[0];
  int idx = blockIdx.x*256 + threadIdx.x;    // 0 .. 2048*1024
  int m = idx >> 10, c = idx & 1023;
  float v;
  if (c < 512){
    int b = m >> 7;
    v = ld(h0, b*512 + c, f32) + ld(c0, b*512 + c, f32);
  } else {
    v = ld(emb, (long)x[m]*512 + (c - 512), f32);
  }
  bf16 bv = f2b(v);
  lstm_input[idx] = bv;
  att_ws[(long)m*1536 + 512 + c] = bv;
  if (idx < 8192){
    float hv = ld(h0, idx, f32), cv = ld(c0, idx, f32);
    hbuf[idx] = f2b(hv);                 // slot 0 of h history
    state0[idx] = hv;
    state0[8192 + idx] = cv;
  }
}

// ---------------------------------------------------------- enc sum + T
// enc[b,s,h] = eo[b*S*H + s*H + h] + eo[B*S*H + b*S*H + s*H + h]; encT[b][h][s]
__global__ void k_encT(const void* __restrict__ eo, const int* __restrict__ flags,
                       bf16* __restrict__ encT){
  __shared__ float tile[32][33];
  int f32 = flags[0];
  int b = blockIdx.z;
  int s0 = blockIdx.x*32, h0 = blockIdx.y*32;
  int tx = threadIdx.x, ty = threadIdx.y;   // (32,8)
  #pragma unroll
  for (int j=0;j<4;j++){
    int s = s0 + ty + j*8;
    long o = (long)b*262144 + (long)s*512 + h0 + tx;
    tile[ty + j*8][tx] = ld(eo, o, f32) + ld(eo, 4194304 + o, f32);
  }
  __syncthreads();
  #pragma unroll
  for (int j=0;j<4;j++){
    int h = h0 + ty + j*8;
    encT[((long)b*512 + h)*512 + s0 + tx] = f2b(tile[tx][ty + j*8]);
  }
}

// --------------------------------------------------------- transpose -> bf16
__global__ void k_tr(const void* __restrict__ in, bf16* __restrict__ out,
                     int R, int C, const int* __restrict__ flags){
  __shared__ float tile[32][33];
  int f32 = flags[0];
  int c0 = blockIdx.x*32, r0 = blockIdx.y*32;
  int tx = threadIdx.x, ty = threadIdx.y;   // (32,8)
  #pragma unroll
  for (int j=0;j<4;j++)
    tile[ty+j*8][tx] = ld(in, (long)(r0+ty+j*8)*C + c0+tx, f32);
  __syncthreads();
  #pragma unroll
  for (int j=0;j<4;j++)
    out[(long)(c0+ty+j*8)*R + r0+tx] = f2b(tile[tx][ty+j*8]);
}

// --------------------------------------------------------- flat convert
__global__ void k_cvtW(const void* __restrict__ w, const int* __restrict__ flags,
                       bf16* __restrict__ out, long n){
  int f32 = flags[0];
  long i = (long)blockIdx.x*256 + threadIdx.x;
  if (i < n) out[i] = f2b(ld(w, i, f32));
}

// biases -> bb: [0]=ih(2048) [2048]=hh(2048) [4096]=att(512) [4608]=align(512) [5120]=out(32000)
__global__ void k_cvt(const void* bih, const void* bhh, const void* batt,
                      const void* balign, const void* bout,
                      const int* __restrict__ flags, bf16* __restrict__ bb){
  int f32 = flags[0];
  int i = blockIdx.x*256 + threadIdx.x;
  if (i < 2048)      bb[i] = f2b(ld(bih, i, f32));
  else if (i < 4096) bb[i] = f2b(ld(bhh, i-2048, f32));
  else if (i < 4608) bb[i] = f2b(ld(batt, i-4096, f32));
  else if (i < 5120) bb[i] = f2b(ld(balign, i-4608, f32));
  else if (i < 37120) bb[i] = f2b(ld(bout, i-5120, f32));
}

// -------------------------------------------------- W_hh fragment swizzle
__global__ void k_wswz(const void* __restrict__ whh, const int* __restrict__ flags,
                       bf16* __restrict__ wsw){
  int f32 = flags[0];
  int bid = blockIdx.x;          // 2048
  int l = threadIdx.x;           // 64
  int p = bid >> 7, tt = (bid >> 4) & 7, ks = bid & 15;
  int g = tt >> 1, hh = tt & 1;
  int row = g*512 + p*32 + hh*16 + (l & 15);
  int k = ks*32 + (l >> 4)*8;
  #pragma unroll
  for (int j=0;j<8;j++)
    wsw[(long)(bid*64 + l)*8 + j] = f2b(ld(whh, (long)row*512 + k + j, f32));
}

// ---------------------------------------------------------------- GEMM
// NT: C[M,N] = A[M,K]*B[N,K]^T, A/B internal bf16 K-contiguous. 128x128 tile, BK=32.
#define M_GX    0
#define M_F32   1
#define M_BF16  2
#define M_ALIGN 3
#define M_OUT   4

template<int MODE>
__global__ void __launch_bounds__(256)
k_gemm(const bf16* __restrict__ A, const bf16* __restrict__ Bm, int K,
       float* __restrict__ outF, bf16* __restrict__ outBH, void* __restrict__ outO,
       int ldc, const bf16* __restrict__ bias1, const bf16* __restrict__ bias2,
       const bf16* __restrict__ alin, bf16* __restrict__ finin,
       const int* __restrict__ flags, long aZ, long bZ, long cZ){
  __shared__ __align__(16) bf16 As[128*32];
  __shared__ __align__(16) bf16 Bs[128*32];
  int dfl = 0;
  if constexpr (MODE == M_OUT) dfl = flags[0];
  int tid = threadIdx.x;
  int w = tid >> 6, l = tid & 63;
  int bm = blockIdx.x, bn = blockIdx.y, bz = blockIdx.z;
  const bf16* Ag = A + bz*aZ + (long)(bm*128 + (tid>>2))*K + (tid&3)*8;
  const bf16* Bg = Bm + bz*bZ + (long)(bn*128 + (tid>>2))*K + (tid&3)*8;
  int m0 = (w&1)*64, n0 = (w>>1)*64;
  floatx4 acc[4][4];
  #pragma unroll
  for (int i=0;i<4;i++)
    #pragma unroll
    for (int j=0;j<4;j++){ floatx4 z = {0.f,0.f,0.f,0.f}; acc[i][j] = z; }

  for (int k0=0; k0<K; k0+=32){
    short8 a0 = *(const short8*)(Ag + k0);
    short8 a1 = *(const short8*)(Ag + (long)64*K + k0);
    short8 b0 = *(const short8*)(Bg + k0);
    short8 b1 = *(const short8*)(Bg + (long)64*K + k0);
    __syncthreads();
    *(short8*)(As + tid*8)        = a0;
    *(short8*)(As + 2048 + tid*8) = a1;
    *(short8*)(Bs + tid*8)        = b0;
    *(short8*)(Bs + 2048 + tid*8) = b1;
    __syncthreads();
    short8 af[4], bfr[4];
    #pragma unroll
    for (int i=0;i<4;i++){
      af[i]  = *(const short8*)(As + (m0 + i*16 + (l&15))*32 + (l>>4)*8);
      bfr[i] = *(const short8*)(Bs + (n0 + i*16 + (l&15))*32 + (l>>4)*8);
    }
    #pragma unroll
    for (int i=0;i<4;i++)
      #pragma unroll
      for (int j=0;j<4;j++)
        acc[i][j] = __builtin_amdgcn_mfma_f32_16x16x32_bf16(af[i], bfr[j], acc[i][j], 0,0,0);
  }

  int rbase = (l>>4)*4;
  int cl = l & 15;
  #pragma unroll
  for (int i=0;i<4;i++){
    #pragma unroll
    for (int j=0;j<4;j++){
      int col = bn*128 + n0 + j*16 + cl;
      #pragma unroll
      for (int r=0;r<4;r++){
        int row = bm*128 + m0 + i*16 + rbase + r;
        float v = acc[i][j][r];
        if constexpr (MODE == M_GX){
          v += b2f(bias1[col]) + b2f(bias2[col]);
          int t = row & 127, b = row >> 7;
          outF[(long)(t*16 + b)*2048 + col] = v;
        } else if constexpr (MODE == M_F32){
          v += b2f(bias1[col]);
          outF[(long)row*ldc + col] = v;
        } else if constexpr (MODE == M_BF16){
          outBH[bz*cZ + (long)row*ldc + col] = f2b(v);
        } else if constexpr (MODE == M_ALIGN){
          v += b2f(bias1[col]);
          float sg = 1.0f/(1.0f + __expf(-v));
          float lo = b2f(alin[(long)row*1024 + col]);
          float hb = b2f(alin[(long)row*1024 + 512 + col]);
          finin[(long)row*512 + col] = f2b(lo + hb*sg);
        } else { // M_OUT
          v += b2f(bias1[col]);
          if (dfl) ((float*)outO)[(long)row*ldc + col] = v;
          else     ((bf16*)outO)[(long)row*ldc + col] = f2b(v);
        }
      }
    }
  }
}

// ------------------------------------------------------------- softmax
__global__ void k_softmax(const float* __restrict__ lg, bf16* __restrict__ soft){
  __shared__ float red[256];
  int r = blockIdx.x;
  int tid = threadIdx.x;
  float x0 = lg[(long)r*512 + tid], x1 = lg[(long)r*512 + 256 + tid];
  red[tid] = fmaxf(x0, x1); __syncthreads();
  for (int s=128; s>0; s>>=1){ if (tid<s) red[tid] = fmaxf(red[tid], red[tid+s]); __syncthreads(); }
  float mx = red[0]; __syncthreads();
  float e0 = __expf(x0-mx), e1 = __expf(x1-mx);
  red[tid] = e0+e1; __syncthreads();
  for (int s=128; s>0; s>>=1){ if (tid<s) red[tid] += red[tid+s]; __syncthreads(); }
  float inv = 1.0f/red[0];
  soft[(long)r*512 + tid] = f2b(e0*inv);
  soft[(long)r*512 + 256 + tid] = f2b(e1*inv);
}

// ------------------------------------------------------------- LSTM
// 16 blocks (one per 32-col slice of H), 128 sequential steps.
// Cross-block h exchange per step WITHOUT cache-maintenance ops:
//   - h slice staged in LDS, wave0 stores it write-through to IC
//     (global_store_dwordx4 sc0 sc1), s_waitcnt vmcnt(0), then a RELAXED
//     agent-scope atomic signal. No buffer_wbl2 / buffer_inv per step.
//   - hbuf has a UNIQUE 16KB slot per step (128 slots = 2MB, reuses the
//     final_in region which is dead until after k_lstm): readers' normal
//     loads always miss the (possibly stale) local L2 and hit IC, which
//     the poll has confirmed holds the data -> no acquire needed.
//   - gxT slice for step t+1 is prefetched into registers during step t,
//     hiding the HBM latency under MFMA + exchange.
__global__ void __launch_bounds__(256, 1)
k_lstm(const float* __restrict__ gxT, const bf16* __restrict__ wsw,
       const int* __restrict__ xlen, const float* __restrict__ state0,
       bf16* __restrict__ hbuf, int* __restrict__ flags,
       bf16* __restrict__ att_ws, bf16* __restrict__ align_in){
  int* bar = flags + 1;
  int p = blockIdx.x;
  int tid = threadIdx.x;
  int w = tid >> 6, l = tid & 63;
  __shared__ float gx_sh[16*128];
  __shared__ __align__(16) bf16 hsh[16*32];
  __shared__ int lens[16];
  if (tid < 16) lens[tid] = xlen[tid];

  short8 wfrag[2][16];
  #pragma unroll
  for (int hh=0; hh<2; hh++)
    #pragma unroll
    for (int ks=0; ks<16; ks++)
      wfrag[hh][ks] = ((const short8*)wsw)[((p*8 + (w*2+hh))*16 + ks)*64 + l];

  int b0i = tid >> 5, u = tid & 31;
  int b1i = b0i + 8;
  float h_r0 = state0[b0i*512 + p*32 + u];
  float c_r0 = state0[8192 + b0i*512 + p*32 + u];
  float h_r1 = state0[b1i*512 + p*32 + u];
  float c_r1 = state0[8192 + b1i*512 + p*32 + u];

  // prefetch gx for t=0
  float gr[8];
  #pragma unroll
  for (int rep=0;rep<8;rep++){
    int idx = rep*256 + tid;
    int b = idx >> 7, jl = idx & 127;
    gr[rep] = gxT[(long)b*2048 + (jl>>5)*512 + p*32 + (jl&31)];
  }

  __syncthreads();

  for (int t=0; t<128; t++){
    // (a) prefetched gx -> LDS
    #pragma unroll
    for (int rep=0;rep<8;rep++)
      gx_sh[rep*256 + tid] = gr[rep];
    // (b) issue prefetch of next step's gx (consumed next iteration)
    if (t < 127){
      #pragma unroll
      for (int rep=0;rep<8;rep++){
        int idx = rep*256 + tid;
        int b = idx >> 7, jl = idx & 127;
        gr[rep] = gxT[(long)((t+1)*16 + b)*2048 + (jl>>5)*512 + p*32 + (jl&31)];
      }
    }
    // (c) h fragments from unique slot t (cold lines -> IC) + MFMA
    const bf16* hb = hbuf + (long)t*8192;
    floatx4 acc0 = {0.f,0.f,0.f,0.f};
    floatx4 acc1 = {0.f,0.f,0.f,0.f};
    #pragma unroll
    for (int ks=0; ks<16; ks++){
      short8 afr = *(const short8*)(hb + (l&15)*512 + ks*32 + (l>>4)*8);
      acc0 = __builtin_amdgcn_mfma_f32_16x16x32_bf16(afr, wfrag[0][ks], acc0, 0,0,0);
      acc1 = __builtin_amdgcn_mfma_f32_16x16x32_bf16(afr, wfrag[1][ks], acc1, 0,0,0);
    }
    __syncthreads();
    // (d) accumulate fragments into gates
    #pragma unroll
    for (int r=0; r<4; r++){
      int bb = (l>>4)*4 + r;
      gx_sh[bb*128 + w*32 + (l&15)]      += acc0[r];
      gx_sh[bb*128 + w*32 + 16 + (l&15)] += acc1[r];
    }
    __syncthreads();
    // (e) activations: 2 batches per thread
    {
      float ig = gx_sh[b0i*128 + u],      fg = gx_sh[b0i*128 + 32 + u];
      float gg = gx_sh[b0i*128 + 64 + u], og = gx_sh[b0i*128 + 96 + u];
      bool valid = (t < lens[b0i]);
      float ii = 1.f/(1.f+__expf(-ig)), ff = 1.f/(1.f+__expf(-fg));
      float g2 = tanhf(gg),             oo = 1.f/(1.f+__expf(-og));
      float cn = ff*c_r0 + ii*g2;
      float hn = oo*tanhf(cn);
      if (valid){ c_r0 = cn; h_r0 = hn; }
      float hout = valid ? hn : 0.0f;
      hsh[b0i*32 + u] = f2b(h_r0);
      int row = b0i*128 + t;
      att_ws[(long)row*1536 + p*32 + u]   = f2b(hout);
      align_in[(long)row*1024 + p*32 + u] = f2b(hout);
    }
    {
      float ig = gx_sh[b1i*128 + u],      fg = gx_sh[b1i*128 + 32 + u];
      float gg = gx_sh[b1i*128 + 64 + u], og = gx_sh[b1i*128 + 96 + u];
      bool valid = (t < lens[b1i]);
      float ii = 1.f/(1.f+__expf(-ig)), ff = 1.f/(1.f+__expf(-fg));
      float g2 = tanhf(gg),             oo = 1.f/(1.f+__expf(-og));
      float cn = ff*c_r1 + ii*g2;
      float hn = oo*tanhf(cn);
      if (valid){ c_r1 = cn; h_r1 = hn; }
      float hout = valid ? hn : 0.0f;
      hsh[b1i*32 + u] = f2b(h_r1);
      int row = b1i*128 + t;
      att_ws[(long)row*1536 + p*32 + u]   = f2b(hout);
      align_in[(long)row*1024 + p*32 + u] = f2b(hout);
    }
    __syncthreads();   // hsh ready
    // (f) publish h slice to slot t+1 + barrier
    if (t < 127){
      if (tid < 64){   // wave 0 only (uniform branch)
        int b = tid >> 2, ch = tid & 3;
        intx4 hv = *(const intx4*)(hsh + b*32 + ch*8);
        bf16* dst = hbuf + (long)(t+1)*8192 + b*512 + p*32 + ch*8;
        asm volatile("global_store_dwordx4 %0, %1, off sc0 sc1" :: "v"(dst), "v"(hv) : "memory");
        asm volatile("s_waitcnt vmcnt(0)" ::: "memory");
        if (tid == 0){
          __hip_atomic_fetch_add(bar, 1, __ATOMIC_RELAXED, __HIP_MEMORY_SCOPE_AGENT);
          int target = (t+1)*16;
          while (__hip_atomic_load(bar, __ATOMIC_RELAXED, __HIP_MEMORY_SCOPE_AGENT) < target)
            __builtin_amdgcn_s_sleep(1);
        }
      }
      __syncthreads();
      asm volatile("" ::: "memory");  // no compiler reordering of loads above the barrier
    }
  }
}

// ---------------------------------------------------- final att/targets out
__global__ void k_finout(const bf16* __restrict__ att_ws, const int* __restrict__ flags,
                         void* __restrict__ d_out){
  int f32 = flags[0];
  long i = (long)blockIdx.x*256 + threadIdx.x;  // 3,147,776 total
  if (i < 3145728){
    if (f32) ((float*)d_out)[65536000 + i] = b2f(att_ws[i]);
    else     ((bf16*)d_out)[65536000 + i] = att_ws[i];
  } else if (i < 3147776){
    long j = i - 3145728;
    float tv = (float)(4*((int)j & 127));
    if (f32) ((float*)d_out)[68681728 + j] = tv;
    else     ((bf16*)d_out)[68681728 + j] = f2b(tv);
  }
}

// ---------------------------------------------------------------- launch
extern "C" void kernel_launch(void* const* d_in, const int* in_sizes, int n_in,
                              void* d_out, int out_size, void* d_ws, size_t ws_size,
                              hipStream_t stream){
  const int*  x      = (const int*) d_in[0];
  const int*  xlen   = (const int*) d_in[1];
  const void* h0     = d_in[2];
  const void* c0     = d_in[3];
  const void* eo     = d_in[4];
  const void* emb    = d_in[5];
  const void* W_att  = d_in[6];
  const void* b_att  = d_in[7];
  const void* W_ih   = d_in[8];
  const void* W_hh   = d_in[9];
  const void* b_ih   = d_in[10];
  const void* b_hh   = d_in[11];
  const void* W_align= d_in[12];
  const void* b_align= d_in[13];
  const void* W_out  = d_in[14];
  const void* b_out  = d_in[15];

  char* ws = (char*)d_ws;
  bf16*  lstm_input = (bf16*)(ws + 0);            //  4,194,304
  bf16*  encT       = (bf16*)(ws + 4194304);      //  8,388,608
  bf16*  WattT      = (bf16*)(ws + 12582912);     //  1,572,864
  bf16*  WalignT    = (bf16*)(ws + 14155776);     //  1,048,576
  bf16*  WoutT      = (bf16*)(ws + 15204352);     // 32,768,000
  bf16*  Wsw        = (bf16*)(ws + 47972352);     //  2,097,152
  float* gxT        = (float*)(ws + 50069504);    // 16,777,216
  float* attlog     = (float*)(ws + 66846720);    //  4,194,304
  bf16*  soft       = (bf16*)(ws + 71041024);     //  2,097,152
  bf16*  align_in   = (bf16*)(ws + 73138176);     //  4,194,304
  // h history (128 slots x 16KB = 2MB) shares the final_in region:
  // written by k_prep (slot0) + k_lstm; final_in is produced only AFTER
  // k_lstm by the M_ALIGN gemm, so the lifetimes don't overlap.
  bf16*  final_in   = (bf16*)(ws + 77332480);     //  2,097,152
  bf16*  hbuf       = (bf16*)(ws + 77332480);     //  (aliases final_in)
  bf16*  att_ws     = (bf16*)(ws + 79429632);     //  6,291,456
  bf16*  bb         = (bf16*)(ws + 85721088);     //     74,240
  float* state0     = (float*)(ws + 85795328);    //     65,536
  bf16*  WihB       = (bf16*)(ws + 85893632);     //  4,194,304
  int*   flags      = (int*) (ws + 90087936);     // total ~90.1 MB

  k_detect<<<1, 64, 0, stream>>>((const unsigned short*)h0, flags);
  k_prep<<<8192, 256, 0, stream>>>(x, h0, c0, emb, flags, lstm_input, att_ws, state0, hbuf);
  k_cvt<<<146, 256, 0, stream>>>(b_ih, b_hh, b_att, b_align, b_out, flags, bb);
  k_cvtW<<<8192, 256, 0, stream>>>(W_ih, flags, WihB, 2097152L);
  k_encT<<<dim3(16,16,16), dim3(32,8), 0, stream>>>(eo, flags, encT);
  k_tr<<<dim3(16,48),  dim3(32,8), 0, stream>>>(W_att,   WattT,   1536, 512, flags);
  k_tr<<<dim3(16,32),  dim3(32,8), 0, stream>>>(W_align, WalignT, 1024, 512, flags);
  k_tr<<<dim3(1000,16),dim3(32,8), 0, stream>>>(W_out,   WoutT,   512, 32000, flags);
  k_wswz<<<2048, 64, 0, stream>>>(W_hh, flags, Wsw);

  // gates_x = lstm_input @ W_ih^T + b_ih + b_hh  -> gxT[t*16+b][2048] f32
  k_gemm<M_GX><<<dim3(16,16,1), 256, 0, stream>>>(lstm_input, WihB, 1024,
      gxT, nullptr, nullptr, 0, bb, bb+2048, nullptr, nullptr, flags, 0, 0, 0);

  k_lstm<<<16, 256, 0, stream>>>(gxT, Wsw, xlen, state0, hbuf, flags, att_ws, align_in);

  // att_logits = attention_input @ W_att + b_att  (f32)
  k_gemm<M_F32><<<dim3(16,4,1), 256, 0, stream>>>(att_ws, WattT, 1536,
      attlog, nullptr, nullptr, 512, bb+4096, nullptr, nullptr, nullptr, flags, 0, 0, 0);

  k_softmax<<<2048, 256, 0, stream>>>(attlog, soft);

  // h_t_bar[b] = soft[b] @ enc[b]  -> align_in cols 512:1024
  k_gemm<M_BF16><<<dim3(1,4,16), 256, 0, stream>>>(soft, encT, 512,
      nullptr, align_in + 512, nullptr, 1024, nullptr, nullptr, nullptr, nullptr,
      flags, 65536L, 262144L, 131072L);

  // aligned = sigmoid(align_in @ W_align + b_align); final_in = lo + hb*aligned
  k_gemm<M_ALIGN><<<dim3(16,4,1), 256, 0, stream>>>(align_in, WalignT, 1024,
      nullptr, nullptr, nullptr, 0, bb+4608, nullptr, align_in, final_in, flags, 0, 0, 0);

  // out = final_in @ W_out + b_out
  k_gemm<M_OUT><<<dim3(16,250,1), 256, 0, stream>>>(final_in, WoutT, 512,
      nullptr, nullptr, d_out, 32000, bb+5120, nullptr, nullptr, nullptr, flags, 0, 0, 0);

  k_finout<<<12296, 256, 0, stream>>>(att_ws, flags, d_out);
}